// Round 8
// baseline (282.409 us; speedup 1.0000x reference)
//
#include <hip/hip_runtime.h>
#include <hip/hip_fp16.h>

// Problem constants
#define N_NODES 100000
#define N_EDGES 3200000
#define IN_F    128
#define HID     3
#define OUT_F   4

// 2D tiling
#define DSH     10
#define DTILE   1024
#define DMASK   1023
#define NSTRIPE 98                         // ceil(100000/1024)
#define SSH     12
#define STILE   4096
#define SMASK   4095
#define NTILE   25                         // ceil(100000/4096)
#define NCH     16                         // chunks per stripe for pass-2

// pass-1 partition
#define NBLKA   1024
#define THRA    256
#define EPB     ((N_EDGES + NBLKA - 1) / NBLKA)     // 3125
#define N1      (NSTRIPE * NBLKA)                    // 100352

#define SCAN_ITEMS 16
#define SCAN_BLOCK 256
#define SCAN_PER_BLOCK (SCAN_ITEMS * SCAN_BLOCK)     // 4096
#define NS1 ((N1 + SCAN_PER_BLOCK - 1) / SCAN_PER_BLOCK)  // 25

#define PSZ (NSTRIPE * DTILE * 3)          // 301056 floats per partial

typedef float f32x4 __attribute__((ext_vector_type(4)));

// ---------------- xw = x @ W ---------------------------------------------
__global__ void xw_kernel(const float* __restrict__ x,
                          const float* __restrict__ W,
                          float* __restrict__ xw) {
    int wave = threadIdx.x >> 6;
    int lane = threadIdx.x & 63;
    int half = lane >> 5;
    int l    = lane & 31;
    int node = blockIdx.x * 8 + wave * 2 + half;
    if (node >= N_NODES) return;
    f32x4 xv = __builtin_nontemporal_load(
        reinterpret_cast<const f32x4*>(x + (size_t)node * IN_F + l * 4));
    const float* w = W + l * 4 * HID;
    float s0 = xv.x * w[0] + xv.y * w[3] + xv.z * w[6] + xv.w * w[9];
    float s1 = xv.x * w[1] + xv.y * w[4] + xv.z * w[7] + xv.w * w[10];
    float s2 = xv.x * w[2] + xv.y * w[5] + xv.z * w[8] + xv.w * w[11];
    #pragma unroll
    for (int off = 16; off > 0; off >>= 1) {
        s0 += __shfl_down(s0, off, 32);
        s1 += __shfl_down(s1, off, 32);
        s2 += __shfl_down(s2, off, 32);
    }
    if (l == 0) {
        xw[node * 3 + 0] = s0;
        xw[node * 3 + 1] = s1;
        xw[node * 3 + 2] = s2;
    }
}

// ---------- hist1: per-block histogram over 98 dst-stripes ---------------
__global__ __launch_bounds__(THRA) void hist1_kernel(const int* __restrict__ col,
                                                     int* __restrict__ histG) {
    __shared__ int hist[8 * NSTRIPE];
    int tid = threadIdx.x, blk = blockIdx.x;
    for (int i = tid; i < 8 * NSTRIPE; i += THRA) hist[i] = 0;
    __syncthreads();
    int start = blk * EPB, end = min(start + EPB, N_EDGES);
    for (int e = start + tid; e < end; e += THRA)
        atomicAdd(&hist[(tid & 7) * NSTRIPE +
                        (__builtin_nontemporal_load(&col[e]) >> DSH)], 1);
    __syncthreads();
    for (int s = tid; s < NSTRIPE; s += THRA) {
        int v = 0;
        #pragma unroll
        for (int r = 0; r < 8; ++r) v += hist[r * NSTRIPE + s];
        histG[s * NBLKA + blk] = v;
    }
}

// ---------------- exclusive scan over histG[N1] --------------------------
__global__ void scan1_kernel(int* __restrict__ data, int* __restrict__ bsum) {
    __shared__ int s[SCAN_BLOCK];
    int tid = threadIdx.x;
    int base = blockIdx.x * SCAN_PER_BLOCK + tid * SCAN_ITEMS;
    int v[SCAN_ITEMS];
    int tsum = 0;
    #pragma unroll
    for (int j = 0; j < SCAN_ITEMS; ++j) {
        v[j] = (base + j < N1) ? data[base + j] : 0;
        tsum += v[j];
    }
    s[tid] = tsum;
    __syncthreads();
    for (int off = 1; off < SCAN_BLOCK; off <<= 1) {
        int t = (tid >= off) ? s[tid - off] : 0;
        __syncthreads();
        s[tid] += t;
        __syncthreads();
    }
    int run = s[tid] - tsum;
    #pragma unroll
    for (int j = 0; j < SCAN_ITEMS; ++j) {
        int t = v[j];
        if (base + j < N1) data[base + j] = run;
        run += t;
    }
    if (tid == SCAN_BLOCK - 1) bsum[blockIdx.x] = s[SCAN_BLOCK - 1];
}

__global__ void scan2_kernel(int* __restrict__ bsum) {
    __shared__ int s[SCAN_BLOCK];
    int tid = threadIdx.x;
    int v = (tid < NS1) ? bsum[tid] : 0;
    s[tid] = v;
    __syncthreads();
    for (int off = 1; off < SCAN_BLOCK; off <<= 1) {
        int t = (tid >= off) ? s[tid - off] : 0;
        __syncthreads();
        s[tid] += t;
        __syncthreads();
    }
    if (tid < NS1) bsum[tid] = s[tid] - v;
}

__global__ void scan3_kernel(int* __restrict__ data, const int* __restrict__ bsum) {
    int i = blockIdx.x * blockDim.x + threadIdx.x;
    if (i < N1) data[i] += bsum[i / SCAN_PER_BLOCK];
}

// ---------- fill1: scatter packed1 = (r<<10 | ldst) by dst-stripe --------
__global__ __launch_bounds__(THRA) void fill1_kernel(const int* __restrict__ row,
                                                     const int* __restrict__ col,
                                                     const int* __restrict__ histG,
                                                     int* __restrict__ packed1) {
    __shared__ int offs[NSTRIPE];
    int tid = threadIdx.x, blk = blockIdx.x;
    for (int i = tid; i < NSTRIPE; i += THRA) offs[i] = histG[i * NBLKA + blk];
    __syncthreads();
    int start = blk * EPB, end = min(start + EPB, N_EDGES);
    for (int e = start + tid; e < end; e += THRA) {
        int c = __builtin_nontemporal_load(&col[e]);
        int r = __builtin_nontemporal_load(&row[e]);
        int s = c >> DSH;
        int pos = atomicAdd(&offs[s], 1);
        packed1[pos] = (r << DSH) | (c & DMASK);
    }
}

// ---------- prep: per-stripe degree -> tab, plus (tile,chunk) hist+scan --
__global__ __launch_bounds__(1024) void prep_kernel(const int* __restrict__ histG,
                                                    const int* __restrict__ packed1,
                                                    const float* __restrict__ xw,
                                                    uint2* __restrict__ tab,
                                                    int* __restrict__ off2) {
    __shared__ int cnt[DTILE];
    __shared__ int h2[NTILE * NCH];     // [tile][chunk]
    __shared__ int sc[NTILE * NCH];
    int tid = threadIdx.x, s = blockIdx.x;
    for (int i = tid; i < DTILE; i += 1024) cnt[i] = 0;
    if (tid < NTILE * NCH) h2[tid] = 0;
    __syncthreads();
    int seg0 = histG[s * NBLKA];
    int seg1 = (s + 1 < NSTRIPE) ? histG[(s + 1) * NBLKA] : N_EDGES;
    int seglen = seg1 - seg0;
    int chsz = (seglen + NCH - 1) / NCH;
    if (chsz == 0) chsz = 1;
    for (int i = seg0 + tid; i < seg1; i += 1024) {
        int p = __builtin_nontemporal_load(&packed1[i]);
        atomicAdd(&cnt[p & DMASK], 1);
        int t = p >> (DSH + SSH);          // src tile
        int ch = (i - seg0) / chsz;
        atomicAdd(&h2[t * NCH + ch], 1);
    }
    __syncthreads();
    // exclusive scan over h2[400] (tile-major linear order)
    if (tid < NTILE * NCH) sc[tid] = h2[tid];
    __syncthreads();
    for (int off = 1; off < NTILE * NCH; off <<= 1) {
        int v = 0;
        if (tid < NTILE * NCH && tid >= off) v = sc[tid - off];
        __syncthreads();
        if (tid < NTILE * NCH) sc[tid] += v;
        __syncthreads();
    }
    if (tid < NTILE * NCH)
        off2[s * (NTILE * NCH) + tid] = seg0 + sc[tid] - h2[tid];
    // build fp16 table {xw*d, d}
    if (tid < DTILE) {
        int node = s * DTILE + tid;
        if (node < N_NODES) {
            float d = rsqrtf((float)(cnt[tid] + 1));   // +1 self loop
            __half2 lo = __floats2half2_rn(xw[node * 3 + 0] * d, xw[node * 3 + 1] * d);
            __half2 hi = __floats2half2_rn(xw[node * 3 + 2] * d, d);
            uint2 u;
            u.x = *reinterpret_cast<unsigned int*>(&lo);
            u.y = *reinterpret_cast<unsigned int*>(&hi);
            tab[node] = u;
        }
    }
}

// ---------- fill2: within stripe, scatter by src-tile --------------------
__global__ __launch_bounds__(256) void fill2_kernel(const int* __restrict__ histG,
                                                    const int* __restrict__ off2,
                                                    const int* __restrict__ packed1,
                                                    int* __restrict__ packed2) {
    __shared__ int offs[NTILE];
    int tid = threadIdx.x;
    int s = blockIdx.x >> 4;
    int c = blockIdx.x & (NCH - 1);
    int seg0 = histG[s * NBLKA];
    int seg1 = (s + 1 < NSTRIPE) ? histG[(s + 1) * NBLKA] : N_EDGES;
    int seglen = seg1 - seg0;
    int chsz = (seglen + NCH - 1) / NCH;
    if (chsz == 0) chsz = 1;
    if (tid < NTILE) offs[tid] = off2[s * (NTILE * NCH) + tid * NCH + c];
    __syncthreads();
    int lo = seg0 + c * chsz;
    int hi = min(lo + chsz, seg1);
    for (int i = lo + tid; i < hi; i += 256) {
        int p = __builtin_nontemporal_load(&packed1[i]);
        int t = p >> (DSH + SSH);
        int pos = atomicAdd(&offs[t], 1);
        packed2[pos] = (((p >> DSH) & SMASK) << DSH) | (p & DMASK);
    }
}

// ---------- aggF: LDS-staged tile aggregation, no global gathers ---------
__global__ __launch_bounds__(512) void aggF_kernel(const int* __restrict__ histG,
                                                   const int* __restrict__ off2,
                                                   const int* __restrict__ packed2,
                                                   const uint2* __restrict__ tab,
                                                   float* __restrict__ partial) {
    __shared__ uint2 stab[STILE];       // 32 KB
    __shared__ float acc[DTILE * 3];    // 12 KB
    const int tq[5] = {0, 7, 13, 19, 25};
    int tid = threadIdx.x;
    int s = blockIdx.x >> 2;
    int q = blockIdx.x & 3;
    for (int i = tid; i < DTILE * 3; i += 512) acc[i] = 0.f;
    int seg1 = (s + 1 < NSTRIPE) ? histG[(s + 1) * NBLKA] : N_EDGES;
    for (int t = tq[q]; t < tq[q + 1]; ++t) {
        __syncthreads();   // protect stab from previous iter readers / acc init
        for (int i = tid; i < STILE; i += 512) {
            int g = t * STILE + i;
            uint2 u = (g < N_NODES) ? tab[g] : make_uint2(0u, 0u);
            stab[i] = u;
        }
        __syncthreads();
        int b0 = off2[s * (NTILE * NCH) + t * NCH];
        int b1 = (t + 1 < NTILE) ? off2[s * (NTILE * NCH) + (t + 1) * NCH] : seg1;
        for (int i = b0 + tid; i < b1; i += 512) {
            int p = __builtin_nontemporal_load(&packed2[i]);
            uint2 v = stab[p >> DSH];
            __half2 lo = *reinterpret_cast<__half2*>(&v.x);
            __half2 hi = *reinterpret_cast<__half2*>(&v.y);
            float2 f0 = __half22float2(lo);
            float2 f1 = __half22float2(hi);
            int a = (p & DMASK) * 3;
            atomicAdd(&acc[a + 0], f0.x);
            atomicAdd(&acc[a + 1], f0.y);
            atomicAdd(&acc[a + 2], f1.x);
        }
    }
    __syncthreads();
    float* P = partial + (size_t)q * PSZ + (size_t)s * (DTILE * 3);
    for (int i = tid; i < DTILE * 3; i += 512) P[i] = acc[i];
}

// ---------- final: combine partials + self-loop + bias + relu + linear ---
__global__ __launch_bounds__(256) void final_kernel(const float* __restrict__ partial,
                                                    const uint2* __restrict__ tab,
                                                    const float* __restrict__ bb,
                                                    const float* __restrict__ Wout,
                                                    const float* __restrict__ bout,
                                                    float* __restrict__ out) {
    int i = blockIdx.x * 256 + threadIdx.x;
    if (i >= N_NODES) return;
    uint2 u = tab[i];
    __half2 lo = *reinterpret_cast<__half2*>(&u.x);
    __half2 hi = *reinterpret_cast<__half2*>(&u.y);
    float2 f0 = __half22float2(lo);
    float2 f1 = __half22float2(hi);
    float g0 = f0.x, g1 = f0.y, g2 = f1.x;   // self-loop term xwn[c]
    float di = f1.y;
    #pragma unroll
    for (int q = 0; q < 4; ++q) {
        const float* P = partial + (size_t)q * PSZ + (size_t)i * 3;
        g0 += P[0];
        g1 += P[1];
        g2 += P[2];
    }
    float h0 = fmaxf(g0 * di + bb[0], 0.f);
    float h1 = fmaxf(g1 * di + bb[1], 0.f);
    float h2 = fmaxf(g2 * di + bb[2], 0.f);
    out[i * 3 + 0] = h0;
    out[i * 3 + 1] = h1;
    out[i * 3 + 2] = h2;
    float* z = out + (size_t)N_NODES * 3;
    #pragma unroll
    for (int k = 0; k < 4; ++k) {
        z[i * 4 + k] = bout[k] + h0 * Wout[0 * 4 + k] + h1 * Wout[1 * 4 + k]
                                 + h2 * Wout[2 * 4 + k];
    }
}

static inline size_t align256(size_t x) { return (x + 255) & ~(size_t)255; }

extern "C" void kernel_launch(void* const* d_in, const int* in_sizes, int n_in,
                              void* d_out, int out_size, void* d_ws, size_t ws_size,
                              hipStream_t stream) {
    const float* x    = (const float*)d_in[0];
    const int*   ei   = (const int*)d_in[1];
    const float* W    = (const float*)d_in[2];
    const float* b    = (const float*)d_in[3];
    const float* Wout = (const float*)d_in[4];
    const float* bout = (const float*)d_in[5];
    float* out = (float*)d_out;

    char* wsb = (char*)d_ws;
    size_t off = 0;
    int*   histG   = (int*)(wsb + off);  off = align256(off + (size_t)N1 * 4);
    int*   packed1 = (int*)(wsb + off);  off = align256(off + (size_t)N_EDGES * 4);
    int*   packed2 = (int*)(wsb + off);  off = align256(off + (size_t)N_EDGES * 4);
    float* xw      = (float*)(wsb + off); off = align256(off + (size_t)N_NODES * 3 * 4);
    uint2* tab     = (uint2*)(wsb + off); off = align256(off + (size_t)N_NODES * 8);
    int*   off2    = (int*)(wsb + off);  off = align256(off + (size_t)NSTRIPE * NTILE * NCH * 4);
    float* partial = (float*)(wsb + off); off = align256(off + (size_t)4 * PSZ * 4);
    int*   bsum    = (int*)(wsb + off);  off = align256(off + (size_t)NS1 * 4);

    const int* row = ei;
    const int* col = ei + N_EDGES;

    xw_kernel<<<(N_NODES + 7) / 8, 256, 0, stream>>>(x, W, xw);
    hist1_kernel<<<NBLKA, THRA, 0, stream>>>(col, histG);
    scan1_kernel<<<NS1, SCAN_BLOCK, 0, stream>>>(histG, bsum);
    scan2_kernel<<<1, SCAN_BLOCK, 0, stream>>>(bsum);
    scan3_kernel<<<(N1 + 255) / 256, 256, 0, stream>>>(histG, bsum);
    fill1_kernel<<<NBLKA, THRA, 0, stream>>>(row, col, histG, packed1);
    prep_kernel<<<NSTRIPE, 1024, 0, stream>>>(histG, packed1, xw, tab, off2);
    fill2_kernel<<<NSTRIPE * NCH, 256, 0, stream>>>(histG, off2, packed1, packed2);
    aggF_kernel<<<NSTRIPE * 4, 512, 0, stream>>>(histG, off2, packed2, tab, partial);
    final_kernel<<<(N_NODES + 255) / 256, 256, 0, stream>>>(partial, tab, b, Wout, bout, out);
}